// Round 3
// baseline (107.969 us; speedup 1.0000x reference)
//
#include <hip/hip_runtime.h>
#include <cmath>

#define RR 61
#define NCELL 3721          // 61*61
#define KCLS 10
#define DDIM 12288          // 64*64*3

// d_out layout (all float32), concatenated in reference return order
#define OUT_PROB 0
#define OUT_LAB  37210
#define OUT_BOX  74420
#define OUT_VALID 223300

#define WPAD 2052           // per-class LDS plane stride (pad breaks 2048%32==0)

// ---------------- Stage 1: patch GEMM (+bias) + softmax ----------------
// 256 blocks x 1024 threads (1 block/CU). Block = 4 patch-rows x 4 patch-cols.
// W staged in LDS in 6 chunks of 2048x10 (transposed, stride-1 conflict-free
// ds_read_b32), so the hot loop's only global traffic is coalesced x reads.
__global__ __launch_bounds__(1024) void k1_logits(
    const float* __restrict__ x, const float* __restrict__ W,
    const float* __restrict__ b, float* __restrict__ out)
{
    const int tid  = threadIdx.x;
    const int tsub = tid & 255;          // d-lane within row group
    const int wrow = tid >> 8;           // patch-row within block (0..3)
    const int blk  = blockIdx.x;
    const int rg   = blk >> 4;           // row group 0..15
    const int cg   = blk & 15;           // col group 0..15

    __shared__ float wlds[KCLS * WPAD];          // 82 KB
    __shared__ float red[4][4][4][KCLS];         // [wrow][wave][patch][class]

    int r = rg * 4 + wrow; if (r > 60) r = 60;   // clamp (dup work, writes guarded)
    const int c0 = cg * 4;

    float acc[4][KCLS];
#pragma unroll
    for (int p = 0; p < 4; ++p)
#pragma unroll
        for (int k = 0; k < KCLS; ++k) acc[p][k] = 0.0f;

    int coff[4];
#pragma unroll
    for (int p = 0; p < 4; ++p) {
        int c = c0 + p; if (c > 60) c = 60;
        coff[p] = c * 48;                 // *16*3 floats
    }
    const int rbase = r * 49152;          // *16*1024*3

    int i   = (tsub >= 192) ? 1 : 0;      // row-in-patch for d = tsub
    int rem = tsub - i * 192;             // 3*j + ch

    for (int chunk = 0; chunk < 6; ++chunk) {
        __syncthreads();                  // previous chunk's LDS reads done
        // stage W[chunk*2048 .. +2048) transposed into LDS (coalesced global)
        for (int f = tid; f < 20480; f += 1024) {
            const int ff = chunk * 20480 + f;
            const int d  = ff / 10;
            const int kk = ff - d * 10;
            wlds[kk * WPAD + (d - (chunk << 11))] = W[ff];
        }
        __syncthreads();

#pragma unroll
        for (int it = 0; it < 8; ++it) {
            const int dl = tsub + (it << 8);
            const float* xp = x + rbase + i * 3072 + rem;
            float xv[4];
#pragma unroll
            for (int p = 0; p < 4; ++p) xv[p] = xp[coff[p]];
            float wv[KCLS];
#pragma unroll
            for (int k = 0; k < KCLS; ++k) wv[k] = wlds[k * WPAD + dl];
#pragma unroll
            for (int p = 0; p < 4; ++p)
#pragma unroll
                for (int k = 0; k < KCLS; ++k) acc[p][k] += xv[p] * wv[k];

            // d += 256  ->  rem += 64 (mod 192), i += 1 or 2
            rem += 64; ++i;
            if (rem >= 192) { rem -= 192; ++i; }
        }
    }

    // 64-lane wave reduction
#pragma unroll
    for (int p = 0; p < 4; ++p)
#pragma unroll
        for (int k = 0; k < KCLS; ++k) {
            float v = acc[p][k];
#pragma unroll
            for (int off = 32; off > 0; off >>= 1) v += __shfl_down(v, off);
            acc[p][k] = v;
        }

    const int wgrp = (tsub >> 6);
    if ((tsub & 63) == 0) {
#pragma unroll
        for (int p = 0; p < 4; ++p)
#pragma unroll
            for (int k = 0; k < KCLS; ++k) red[wrow][wgrp][p][k] = acc[p][k];
    }
    __syncthreads();

    if (tid < 16) {
        const int wr = tid >> 2;          // patch-row
        const int p  = tid & 3;           // patch-col
        const int rr = rg * 4 + wr;
        const int cc = c0 + p;
        if (rr <= 60 && cc <= 60) {
            double l[KCLS];
#pragma unroll
            for (int k = 0; k < KCLS; ++k)
                l[k] = (double)red[wr][0][p][k] + (double)red[wr][1][p][k]
                     + (double)red[wr][2][p][k] + (double)red[wr][3][p][k]
                     + (double)b[k];
            double m = l[0];
#pragma unroll
            for (int k = 1; k < KCLS; ++k) m = fmax(m, l[k]);
            double e[KCLS], s = 0.0;
#pragma unroll
            for (int k = 0; k < KCLS; ++k) { e[k] = exp(l[k] - m); s += e[k]; }
            const double inv = 1.0 / s;
            float* po = out + OUT_PROB + (size_t)(rr * 61 + cc) * KCLS;
#pragma unroll
            for (int k = 0; k < KCLS; ++k) po[k] = (float)(e[k] * inv);
        }
    }
}

// ---------------- Stage 2+3: union-find CC + boxes (one block/class) -------
// Reference: 244-step Jacobi min-propagation -> fixed point = per-component
// min initial label (= min linear idx + 1). Union-find by min index computes
// exactly that root, bit-identical labels, with 3 barriers instead of ~300.
__device__ __forceinline__ int uf_find(int* par, int xx) {
    int x = xx;
    while (true) {
        const int p = ((volatile int*)par)[x];
        if (p == x) return x;
        const int gp = ((volatile int*)par)[p];
        if (gp == p) return p;
        atomicCAS(&par[x], p, gp);   // path-halving; CAS keeps monotone invariant
        x = gp;
    }
}

__device__ __forceinline__ void uf_union(int* par, int a, int b) {
    int ra = uf_find(par, a);
    int rb = uf_find(par, b);
    while (ra != rb) {
        if (ra < rb) { const int t = ra; ra = rb; rb = t; }   // ra > rb
        const int old = atomicMin(&par[ra], rb);
        if (old == ra || old == rb) break;   // linked (or already linked)
        const int hi = old > rb ? old : rb;
        const int lo = old ^ rb ^ hi;
        ra = uf_find(par, hi);
        rb = uf_find(par, lo);
    }
}

__global__ __launch_bounds__(1024) void k2_cc_boxes(float* __restrict__ out)
{
    const int k   = blockIdx.x;
    const int tid = threadIdx.x;

    __shared__ int par[NCELL];
    __shared__ int rmn[NCELL + 1], rmx[NCELL + 1], cmn[NCELL + 1], cmx[NCELL + 1];

    for (int s = tid; s <= NCELL; s += 1024) {
        rmn[s] = 0x7fffffff; cmn[s] = 0x7fffffff; rmx[s] = -1; cmx[s] = -1;
    }
    // init parents from mask
    for (int idx = tid; idx < NCELL; idx += 1024) {
        const float pv = out[OUT_PROB + (size_t)idx * KCLS + k];
        par[idx] = (pv > 0.7f) ? idx : -1;
    }
    __syncthreads();

    // union with left/up neighbors (2 edges/cell cover 4-connectivity)
    for (int idx = tid; idx < NCELL; idx += 1024) {
        if (par[idx] < 0) continue;
        const int r = idx / 61, c = idx - r * 61;
        if (c > 0  && par[idx - 1]  >= 0) uf_union(par, idx, idx - 1);
        if (r > 0  && par[idx - 61] >= 0) uf_union(par, idx, idx - 61);
    }
    __syncthreads();

    // labels + box accumulation
    for (int idx = tid; idx < NCELL; idx += 1024) {
        int lab = 0;
        if (par[idx] >= 0) {
            const int root = uf_find(par, idx);
            lab = root + 1;
            const int r = idx / 61, c = idx - r * 61;
            atomicMin(&rmn[lab], r); atomicMax(&rmx[lab], r);
            atomicMin(&cmn[lab], c); atomicMax(&cmx[lab], c);
        }
        out[OUT_LAB + (size_t)idx * KCLS + k] = (float)lab;
    }
    __syncthreads();

    // boxes + valid (every slot written every launch: d_out is re-poisoned)
    for (int s = tid; s <= NCELL; s += 1024) {
        const bool val = (s > 0) && (rmx[s] >= 0);
        float* bo = out + OUT_BOX + (size_t)(k * (NCELL + 1) + s) * 4;
        if (val) {
            bo[0] = (float)(rmn[s] - 1);
            bo[1] = (float)(cmn[s] - 1);
            bo[2] = (float)(rmx[s] + 1);
            bo[3] = (float)(cmx[s] + 1);
        } else {
            bo[0] = 0.0f; bo[1] = 0.0f; bo[2] = 0.0f; bo[3] = 0.0f;
        }
        out[OUT_VALID + (size_t)k * (NCELL + 1) + s] = val ? 1.0f : 0.0f;
    }
}

extern "C" void kernel_launch(void* const* d_in, const int* in_sizes, int n_in,
                              void* d_out, int out_size, void* d_ws, size_t ws_size,
                              hipStream_t stream) {
    const float* x = (const float*)d_in[0];   // (1,1024,1024,3) f32
    const float* W = (const float*)d_in[1];   // (12288,10) f32
    const float* b = (const float*)d_in[2];   // (10,) f32
    float* out = (float*)d_out;

    k1_logits  <<<dim3(256), dim3(1024), 0, stream>>>(x, W, b, out);
    k2_cc_boxes<<<dim3(KCLS), dim3(1024), 0, stream>>>(out);
}